// Round 1
// baseline (337.844 us; speedup 1.0000x reference)
//
#include <hip/hip_runtime.h>

typedef __attribute__((ext_vector_type(8))) short short8;
typedef __attribute__((ext_vector_type(4))) short short4v;
typedef __attribute__((ext_vector_type(4))) float f32x4;

static __device__ __forceinline__ unsigned short f2bf(float f) {
  unsigned int u = __float_as_uint(f);
  u += 0x7fffu + ((u >> 16) & 1u);
  return (unsigned short)(u >> 16);
}

// ---------------- converts ----------------
__global__ void conv_bf16_kernel(const float* __restrict__ in,
                                 unsigned short* __restrict__ out, int n) {
  int i = (blockIdx.x * blockDim.x + threadIdx.x) * 4;
  if (i >= n) return;
  float4 v = *(const float4*)(in + i);
  short4v o;
  o[0] = (short)f2bf(v.x); o[1] = (short)f2bf(v.y);
  o[2] = (short)f2bf(v.z); o[3] = (short)f2bf(v.w);
  *(short4v*)(out + i) = o;
}

// W [K=1024,N=1024] fp32 -> Wt [N,K] bf16
__global__ void wtrans_kernel(const float* __restrict__ W,
                              unsigned short* __restrict__ Wt) {
  __shared__ float t[32][33];
  int n0 = blockIdx.x * 32, k0 = blockIdx.y * 32;
#pragma unroll
  for (int j = 0; j < 4; ++j)
    t[threadIdx.y + j * 8][threadIdx.x] =
        W[(size_t)(k0 + threadIdx.y + j * 8) * 1024 + n0 + threadIdx.x];
  __syncthreads();
#pragma unroll
  for (int j = 0; j < 4; ++j)
    Wt[(size_t)(n0 + threadIdx.y + j * 8) * 1024 + k0 + threadIdx.x] =
        f2bf(t[threadIdx.x][threadIdx.y + j * 8]);
}

__global__ void mask_kernel(const float* __restrict__ e, float* __restrict__ mb, int n) {
  int i = blockIdx.x * blockDim.x + threadIdx.x;
  if (i < n) mb[i] = (fabsf(e[i]) > 0.1f) ? 0.0f : -1e30f;
}

// ---------------- GEMM: C[M=8192,N=1024] = X @ Wt^T + bias ----------------
// X bf16 [M,1024] row-major, Wt bf16 [1024(N),1024(K)] row-major.
// MODE 0: write bf16 [B,H,L,64]   (Q, K)
// MODE 1: write bf16 [B,H,64,S]   (V transposed)
// MODE 2: write fp32 [M,1024]     (final output)
template <int MODE>
__global__ __launch_bounds__(256) void gemm128_kernel(
    const unsigned short* __restrict__ X, const unsigned short* __restrict__ Wt,
    const float* __restrict__ bias, void* __restrict__ outp) {
  const int K = 1024;
  __shared__ unsigned short Al[128 * 40];  // +8 pad: 2-way-max bank aliasing
  __shared__ unsigned short Bl[128 * 40];
  const int m0 = blockIdx.x * 128, n0 = blockIdx.y * 128;
  const int tid = threadIdx.x, lane = tid & 63, wid = tid >> 6;
  const int wr = wid >> 1, wc = wid & 1;
  const int g = lane >> 4, lr = lane & 15;
  const f32x4 fz = {0.f, 0.f, 0.f, 0.f};
  f32x4 acc[4][4];
#pragma unroll
  for (int i = 0; i < 4; i++)
#pragma unroll
    for (int j = 0; j < 4; j++) acc[i][j] = fz;
  const int srow = tid >> 2;        // 0..63
  const int skc = (tid & 3) * 8;    // 0,8,16,24

  for (int k0 = 0; k0 < K; k0 += 32) {
#pragma unroll
    for (int p = 0; p < 2; ++p) {
      int row = srow + p * 64;
      *(short8*)(Al + row * 40 + skc) =
          *(const short8*)(X + (size_t)(m0 + row) * K + k0 + skc);
      *(short8*)(Bl + row * 40 + skc) =
          *(const short8*)(Wt + (size_t)(n0 + row) * K + k0 + skc);
    }
    __syncthreads();
    short8 a[4], b[4];
#pragma unroll
    for (int i = 0; i < 4; i++)
      a[i] = *(const short8*)(Al + (wr * 64 + i * 16 + lr) * 40 + g * 8);
#pragma unroll
    for (int i = 0; i < 4; i++)
      b[i] = *(const short8*)(Bl + (wc * 64 + i * 16 + lr) * 40 + g * 8);
#pragma unroll
    for (int i = 0; i < 4; i++)
#pragma unroll
      for (int j = 0; j < 4; j++)
        acc[i][j] = __builtin_amdgcn_mfma_f32_16x16x32_bf16(a[i], b[j], acc[i][j], 0, 0, 0);
    __syncthreads();
  }

#pragma unroll
  for (int i = 0; i < 4; i++) {
    const int mrow0 = m0 + wr * 64 + i * 16 + g * 4;
#pragma unroll
    for (int j = 0; j < 4; j++) {
      const int ncol = n0 + wc * 64 + j * 16 + lr;
      const float bv = bias[ncol];
      if (MODE == 2) {
        float* out = (float*)outp;
#pragma unroll
        for (int e = 0; e < 4; e++)
          out[(size_t)(mrow0 + e) * 1024 + ncol] = acc[i][j][e] + bv;
      } else if (MODE == 0) {
        unsigned short* out = (unsigned short*)outp;
        const int h = ncol >> 6, dh = ncol & 63;
#pragma unroll
        for (int e = 0; e < 4; e++) {
          int mrow = mrow0 + e;
          int b_ = mrow >> 11, l = mrow & 2047;
          out[((size_t)(b_ * 16 + h) * 2048 + l) * 64 + dh] = f2bf(acc[i][j][e] + bv);
        }
      } else {
        unsigned short* out = (unsigned short*)outp;
        const int h = ncol >> 6, d = ncol & 63;
        const int b_ = mrow0 >> 11, s = mrow0 & 2047;  // 4 consecutive s, 4-aligned
        short4v pk;
#pragma unroll
        for (int e = 0; e < 4; e++) pk[e] = (short)f2bf(acc[i][j][e] + bv);
        *(short4v*)(out + ((size_t)(b_ * 16 + h) * 64 + d) * 2048 + s) = pk;
      }
    }
  }
}

// ---------------- flash attention ----------------
// Qh,Kh: [B,H,S,64] bf16; Vt: [B,H,64,S] bf16; mb: [B,S] fp32 bias (0/-1e30)
// AO: [B*L, 1024] bf16. Grid: (L/128, B*H), 256 threads (4 waves x 32 q-rows).
// Swapped QK^T: st = mfma(Kfrag, Qfrag) -> lane holds P values for ONE q (col=lr).
__global__ __launch_bounds__(256) void attn_kernel(
    const unsigned short* __restrict__ Qh, const unsigned short* __restrict__ Kh,
    const unsigned short* __restrict__ Vt, const float* __restrict__ mb,
    unsigned short* __restrict__ AO) {
  const int S = 2048, Dh = 64;
  const int bh = blockIdx.y, b_ = bh >> 4, h = bh & 15;
  const unsigned short* Qp = Qh + (size_t)bh * S * Dh;
  const unsigned short* Kp = Kh + (size_t)bh * S * Dh;
  const unsigned short* Vp = Vt + (size_t)bh * Dh * S;
  const float* mbp = mb + b_ * S;
  const int tid = threadIdx.x, lane = tid & 63, wid = tid >> 6;
  const int g = lane >> 4, lr = lane & 15;
  const int qbase = blockIdx.x * 128 + wid * 32;

  __shared__ unsigned short Kl[32 * 72];  // [s][72]: 144B rows, 16B aligned, 2-way banks
  __shared__ unsigned short Vl[64 * 40];  // [d][40]: 80B rows, 16B aligned

  short8 qf[2][2];
#pragma unroll
  for (int qt = 0; qt < 2; qt++)
#pragma unroll
    for (int kh = 0; kh < 2; kh++)
      qf[qt][kh] = *(const short8*)(Qp + (size_t)(qbase + qt * 16 + lr) * Dh + kh * 32 + g * 8);

  const f32x4 fz = {0.f, 0.f, 0.f, 0.f};
  f32x4 o[2][4];
#pragma unroll
  for (int qt = 0; qt < 2; qt++)
#pragma unroll
    for (int t = 0; t < 4; t++) o[qt][t] = fz;
  float mrun[2] = {-1e30f, -1e30f}, lrun[2] = {0.f, 0.f};

  for (int s0 = 0; s0 < S; s0 += 32) {
    {
      int s_ = tid >> 3, kc = (tid & 7) * 8;
      *(short8*)(Kl + s_ * 72 + kc) = *(const short8*)(Kp + (size_t)(s0 + s_) * Dh + kc);
      int d_ = tid >> 2, sc = (tid & 3) * 8;
      *(short8*)(Vl + d_ * 40 + sc) = *(const short8*)(Vp + (size_t)d_ * S + s0 + sc);
    }
    __syncthreads();

    short8 kf[2][2];
#pragma unroll
    for (int st = 0; st < 2; st++)
#pragma unroll
      for (int kh = 0; kh < 2; kh++)
        kf[st][kh] = *(const short8*)(Kl + (st * 16 + lr) * 72 + kh * 32 + g * 8);
    short8 vf[4];
#pragma unroll
    for (int t = 0; t < 4; t++) {
      short4v lo = *(const short4v*)(Vl + (t * 16 + lr) * 40 + g * 4);
      short4v hi = *(const short4v*)(Vl + (t * 16 + lr) * 40 + 16 + g * 4);
      short8 v;
      v[0] = lo[0]; v[1] = lo[1]; v[2] = lo[2]; v[3] = lo[3];
      v[4] = hi[0]; v[5] = hi[1]; v[6] = hi[2]; v[7] = hi[3];
      vf[t] = v;
    }
    f32x4 mlo = *(const f32x4*)(mbp + s0 + 4 * g);
    f32x4 mhi = *(const f32x4*)(mbp + s0 + 16 + 4 * g);

#pragma unroll
    for (int qt = 0; qt < 2; qt++) {
      f32x4 sa = __builtin_amdgcn_mfma_f32_16x16x32_bf16(kf[0][0], qf[qt][0], fz, 0, 0, 0);
      sa = __builtin_amdgcn_mfma_f32_16x16x32_bf16(kf[0][1], qf[qt][1], sa, 0, 0, 0);
      f32x4 sb = __builtin_amdgcn_mfma_f32_16x16x32_bf16(kf[1][0], qf[qt][0], fz, 0, 0, 0);
      sb = __builtin_amdgcn_mfma_f32_16x16x32_bf16(kf[1][1], qf[qt][1], sb, 0, 0, 0);
      float va[4], vb[4];
#pragma unroll
      for (int i = 0; i < 4; i++) {
        va[i] = sa[i] * 0.125f + mlo[i];
        vb[i] = sb[i] * 0.125f + mhi[i];
      }
      float mx = fmaxf(fmaxf(fmaxf(va[0], va[1]), fmaxf(va[2], va[3])),
                       fmaxf(fmaxf(vb[0], vb[1]), fmaxf(vb[2], vb[3])));
      mx = fmaxf(mx, __shfl_xor(mx, 16));
      mx = fmaxf(mx, __shfl_xor(mx, 32));
      float mnew = fmaxf(mrun[qt], mx);
      float scale = __expf(mrun[qt] - mnew);
      mrun[qt] = mnew;
      float p[8], ps = 0.f;
#pragma unroll
      for (int i = 0; i < 4; i++) { p[i] = __expf(va[i] - mnew); ps += p[i]; }
#pragma unroll
      for (int i = 0; i < 4; i++) { p[4 + i] = __expf(vb[i] - mnew); ps += p[4 + i]; }
      ps += __shfl_xor(ps, 16);
      ps += __shfl_xor(ps, 32);
      lrun[qt] = lrun[qt] * scale + ps;
      short8 pf;
#pragma unroll
      for (int i = 0; i < 8; i++) pf[i] = (short)f2bf(p[i]);
#pragma unroll
      for (int t = 0; t < 4; t++) {
        o[qt][t] *= scale;
        o[qt][t] = __builtin_amdgcn_mfma_f32_16x16x32_bf16(vf[t], pf, o[qt][t], 0, 0, 0);
      }
    }
    __syncthreads();
  }

#pragma unroll
  for (int qt = 0; qt < 2; qt++) {
    float inv = 1.f / lrun[qt];
    size_t row = (size_t)b_ * 2048 + qbase + qt * 16 + lr;
#pragma unroll
    for (int t = 0; t < 4; t++)
#pragma unroll
      for (int i = 0; i < 4; i++) {
        int d = t * 16 + g * 4 + i;
        AO[row * 1024 + h * 64 + d] = f2bf(o[qt][t][i] * inv);
      }
  }
}

// ---------------- launch ----------------
extern "C" void kernel_launch(void* const* d_in, const int* in_sizes, int n_in,
                              void* d_out, int out_size, void* d_ws, size_t ws_size,
                              hipStream_t stream) {
  const float* q_x = (const float*)d_in[0];
  const float* k_x = (const float*)d_in[1];
  const float* v_x = (const float*)d_in[2];
  const float* energy = (const float*)d_in[3];
  const float* Wq = (const float*)d_in[4];
  const float* bq = (const float*)d_in[5];
  const float* Wk = (const float*)d_in[6];
  const float* bk = (const float*)d_in[7];
  const float* Wv = (const float*)d_in[8];
  const float* bv = (const float*)d_in[9];
  const float* Wo = (const float*)d_in[10];
  const float* bo = (const float*)d_in[11];

  char* w = (char*)d_ws;
  auto take = [&](size_t bytes) {
    char* p = w;
    w += (bytes + 255) & ~(size_t)255;
    return p;
  };
  const size_t XB = (size_t)8192 * 1024 * 2;  // 16.78 MB
  unsigned short* Xq = (unsigned short*)take(XB);
  unsigned short* Xk = (unsigned short*)take(XB);
  unsigned short* Xv = (unsigned short*)take(XB);
  unsigned short* Wtq = (unsigned short*)take((size_t)1024 * 1024 * 2);
  unsigned short* Wtk = (unsigned short*)take((size_t)1024 * 1024 * 2);
  unsigned short* Wtv = (unsigned short*)take((size_t)1024 * 1024 * 2);
  unsigned short* Wto = (unsigned short*)take((size_t)1024 * 1024 * 2);
  float* mb = (float*)take((size_t)4 * 2048 * 4);
  unsigned short* Qh = (unsigned short*)take(XB);
  unsigned short* Kh = (unsigned short*)take(XB);
  unsigned short* Vt = (unsigned short*)take(XB);
  unsigned short* AO = (unsigned short*)take(XB);

  const int NX = 8192 * 1024;
  conv_bf16_kernel<<<NX / 1024, 256, 0, stream>>>(q_x, Xq, NX);
  conv_bf16_kernel<<<NX / 1024, 256, 0, stream>>>(k_x, Xk, NX);
  conv_bf16_kernel<<<NX / 1024, 256, 0, stream>>>(v_x, Xv, NX);
  wtrans_kernel<<<dim3(32, 32), dim3(32, 8), 0, stream>>>(Wq, Wtq);
  wtrans_kernel<<<dim3(32, 32), dim3(32, 8), 0, stream>>>(Wk, Wtk);
  wtrans_kernel<<<dim3(32, 32), dim3(32, 8), 0, stream>>>(Wv, Wtv);
  wtrans_kernel<<<dim3(32, 32), dim3(32, 8), 0, stream>>>(Wo, Wto);
  mask_kernel<<<32, 256, 0, stream>>>(energy, mb, 8192);

  gemm128_kernel<0><<<dim3(64, 8), 256, 0, stream>>>(Xq, Wtq, bq, (void*)Qh);
  gemm128_kernel<0><<<dim3(64, 8), 256, 0, stream>>>(Xk, Wtk, bk, (void*)Kh);
  gemm128_kernel<1><<<dim3(64, 8), 256, 0, stream>>>(Xv, Wtv, bv, (void*)Vt);
  attn_kernel<<<dim3(16, 64), 256, 0, stream>>>(Qh, Kh, Vt, mb, AO);
  gemm128_kernel<2><<<dim3(64, 8), 256, 0, stream>>>(AO, Wto, bo, d_out);
}

// Round 2
// 336.412 us; speedup vs baseline: 1.0043x; 1.0043x over previous
//
#include <hip/hip_runtime.h>
#include <hip/hip_bf16.h>

typedef __attribute__((ext_vector_type(8))) short short8;
typedef __attribute__((ext_vector_type(4))) short short4v;
typedef __attribute__((ext_vector_type(4))) float f32x4;

static __device__ __forceinline__ unsigned short f2bf(float f) {
  unsigned int u = __float_as_uint(f);
  u += 0x7fffu + ((u >> 16) & 1u);
  return (unsigned short)(u >> 16);
}

static __device__ __forceinline__ unsigned pk2bf(float a, float b) {
  union { __hip_bfloat162 h; unsigned u; } v;
  v.h = __float22bfloat162_rn(make_float2(a, b));
  return v.u;
}

static __device__ __forceinline__ f32x4 vmax4(f32x4 a, f32x4 b) {
  f32x4 r;
  r[0] = fmaxf(a[0], b[0]); r[1] = fmaxf(a[1], b[1]);
  r[2] = fmaxf(a[2], b[2]); r[3] = fmaxf(a[3], b[3]);
  return r;
}

// ---------------- converts ----------------
__global__ void conv_bf16_kernel(const float* __restrict__ in,
                                 unsigned short* __restrict__ out, int n) {
  int i = (blockIdx.x * blockDim.x + threadIdx.x) * 4;
  if (i >= n) return;
  float4 v = *(const float4*)(in + i);
  short4v o;
  o[0] = (short)f2bf(v.x); o[1] = (short)f2bf(v.y);
  o[2] = (short)f2bf(v.z); o[3] = (short)f2bf(v.w);
  *(short4v*)(out + i) = o;
}

// W [K=1024,N=1024] fp32 -> Wt [N,K] bf16
__global__ void wtrans_kernel(const float* __restrict__ W,
                              unsigned short* __restrict__ Wt) {
  __shared__ float t[32][33];
  int n0 = blockIdx.x * 32, k0 = blockIdx.y * 32;
#pragma unroll
  for (int j = 0; j < 4; ++j)
    t[threadIdx.y + j * 8][threadIdx.x] =
        W[(size_t)(k0 + threadIdx.y + j * 8) * 1024 + n0 + threadIdx.x];
  __syncthreads();
#pragma unroll
  for (int j = 0; j < 4; ++j)
    Wt[(size_t)(n0 + threadIdx.y + j * 8) * 1024 + k0 + threadIdx.x] =
        f2bf(t[threadIdx.x][threadIdx.y + j * 8]);
}

__global__ void mask_kernel(const float* __restrict__ e, float* __restrict__ mb, int n) {
  int i = blockIdx.x * blockDim.x + threadIdx.x;
  if (i < n) mb[i] = (fabsf(e[i]) > 0.1f) ? 0.0f : -1e30f;
}

// ---------------- GEMM: C[M=8192,N=1024] = X @ Wt^T + bias ----------------
template <int MODE>
__global__ __launch_bounds__(256) void gemm128_kernel(
    const unsigned short* __restrict__ X, const unsigned short* __restrict__ Wt,
    const float* __restrict__ bias, void* __restrict__ outp) {
  const int K = 1024;
  __shared__ unsigned short Al[128 * 40];
  __shared__ unsigned short Bl[128 * 40];
  const int m0 = blockIdx.x * 128, n0 = blockIdx.y * 128;
  const int tid = threadIdx.x, lane = tid & 63, wid = tid >> 6;
  const int wr = wid >> 1, wc = wid & 1;
  const int g = lane >> 4, lr = lane & 15;
  const f32x4 fz = {0.f, 0.f, 0.f, 0.f};
  f32x4 acc[4][4];
#pragma unroll
  for (int i = 0; i < 4; i++)
#pragma unroll
    for (int j = 0; j < 4; j++) acc[i][j] = fz;
  const int srow = tid >> 2;
  const int skc = (tid & 3) * 8;

  for (int k0 = 0; k0 < K; k0 += 32) {
#pragma unroll
    for (int p = 0; p < 2; ++p) {
      int row = srow + p * 64;
      *(short8*)(Al + row * 40 + skc) =
          *(const short8*)(X + (size_t)(m0 + row) * K + k0 + skc);
      *(short8*)(Bl + row * 40 + skc) =
          *(const short8*)(Wt + (size_t)(n0 + row) * K + k0 + skc);
    }
    __syncthreads();
    short8 a[4], b[4];
#pragma unroll
    for (int i = 0; i < 4; i++)
      a[i] = *(const short8*)(Al + (wr * 64 + i * 16 + lr) * 40 + g * 8);
#pragma unroll
    for (int i = 0; i < 4; i++)
      b[i] = *(const short8*)(Bl + (wc * 64 + i * 16 + lr) * 40 + g * 8);
#pragma unroll
    for (int i = 0; i < 4; i++)
#pragma unroll
      for (int j = 0; j < 4; j++)
        acc[i][j] = __builtin_amdgcn_mfma_f32_16x16x32_bf16(a[i], b[j], acc[i][j], 0, 0, 0);
    __syncthreads();
  }

#pragma unroll
  for (int i = 0; i < 4; i++) {
    const int mrow0 = m0 + wr * 64 + i * 16 + g * 4;
#pragma unroll
    for (int j = 0; j < 4; j++) {
      const int ncol = n0 + wc * 64 + j * 16 + lr;
      const float bv = bias[ncol];
      if (MODE == 2) {
        float* out = (float*)outp;
#pragma unroll
        for (int e = 0; e < 4; e++)
          out[(size_t)(mrow0 + e) * 1024 + ncol] = acc[i][j][e] + bv;
      } else if (MODE == 0) {
        unsigned short* out = (unsigned short*)outp;
        const int h = ncol >> 6, dh = ncol & 63;
#pragma unroll
        for (int e = 0; e < 4; e++) {
          int mrow = mrow0 + e;
          int b_ = mrow >> 11, l = mrow & 2047;
          out[((size_t)(b_ * 16 + h) * 2048 + l) * 64 + dh] = f2bf(acc[i][j][e] + bv);
        }
      } else {
        unsigned short* out = (unsigned short*)outp;
        const int h = ncol >> 6, d = ncol & 63;
        const int b_ = mrow0 >> 11, s = mrow0 & 2047;
        short4v pk;
#pragma unroll
        for (int e = 0; e < 4; e++) pk[e] = (short)f2bf(acc[i][j][e] + bv);
        *(short4v*)(out + ((size_t)(b_ * 16 + h) * 64 + d) * 2048 + s) = pk;
      }
    }
  }
}

// ---------------- flash attention (KVBLK=64, log2-softmax, defer-max) ----------------
// Qh,Kh: [B,H,S,64] bf16; Vt: [B,H,64,S] bf16; mb: [B,S] fp32 bias (0/-1e30)
// AO: [B*L, 1024] bf16. Grid: (L/128, B*H), 256 threads (4 waves x 32 q-rows).
__global__ __launch_bounds__(256) void attn_kernel(
    const unsigned short* __restrict__ Qh, const unsigned short* __restrict__ Kh,
    const unsigned short* __restrict__ Vt, const float* __restrict__ mb,
    unsigned short* __restrict__ AO) {
  const int S = 2048, Dh = 64;
  const int bh = blockIdx.y, b_ = bh >> 4, h = bh & 15;
  const unsigned short* Qp = Qh + (size_t)bh * S * Dh;
  const unsigned short* Kp = Kh + (size_t)bh * S * Dh;
  const unsigned short* Vp = Vt + (size_t)bh * Dh * S;
  const float* mbp = mb + b_ * S;
  const int tid = threadIdx.x, lane = tid & 63, wid = tid >> 6;
  const int g = lane >> 4, lr = lane & 15;
  const int sw = (lr & 7) << 3;  // XOR swizzle operand (shorts)
  const int qbase = blockIdx.x * 128 + wid * 32;
  const float c2 = 0.18033688011f;  // log2(e) / sqrt(64)

  __shared__ unsigned short Kl[64 * 64];  // [s][d] linear 128B rows, XOR-swizzled
  __shared__ unsigned short Vl[64 * 64];  // [d][s] linear 128B rows, XOR-swizzled

  short8 qf[2][2];
#pragma unroll
  for (int qt = 0; qt < 2; qt++)
#pragma unroll
    for (int kh = 0; kh < 2; kh++)
      qf[qt][kh] = *(const short8*)(Qp + (size_t)(qbase + qt * 16 + lr) * Dh + kh * 32 + g * 8);

  const f32x4 fz = {0.f, 0.f, 0.f, 0.f};
  f32x4 o[2][4];
#pragma unroll
  for (int qt = 0; qt < 2; qt++)
#pragma unroll
    for (int t = 0; t < 4; t++) o[qt][t] = fz;
  float mrun[2] = {-1e28f, -1e28f}, lrun[2] = {0.f, 0.f};

  for (int s0 = 0; s0 < S; s0 += 64) {
    // stage K (64x64) and V (64x64) tiles, 2x16B per thread per buffer
#pragma unroll
    for (int p = 0; p < 2; ++p) {
      int i = p * 256 + tid;
      int r = i >> 3, c16 = i & 7;
      int cs = ((c16 ^ (r & 7)) << 3);
      *(short8*)(Kl + r * 64 + cs) = *(const short8*)(Kp + (size_t)(s0 + r) * 64 + c16 * 8);
      *(short8*)(Vl + r * 64 + cs) = *(const short8*)(Vp + (size_t)r * S + s0 + c16 * 8);
    }
    __syncthreads();

    short8 kf[4][2];
#pragma unroll
    for (int st = 0; st < 4; st++)
#pragma unroll
      for (int kh = 0; kh < 2; kh++)
        kf[st][kh] = *(const short8*)(Kl + (st * 16 + lr) * 64 + ((kh * 32 + g * 8) ^ sw));

    f32x4 mbv[4];
#pragma unroll
    for (int st = 0; st < 4; st++)
      mbv[st] = *(const f32x4*)(mbp + s0 + st * 16 + g * 4);

    f32x4 sc[2][4];
#pragma unroll
    for (int qt = 0; qt < 2; qt++)
#pragma unroll
      for (int st = 0; st < 4; st++) {
        f32x4 a0 = __builtin_amdgcn_mfma_f32_16x16x32_bf16(kf[st][0], qf[qt][0], fz, 0, 0, 0);
        sc[qt][st] = __builtin_amdgcn_mfma_f32_16x16x32_bf16(kf[st][1], qf[qt][1], a0, 0, 0, 0);
      }

    short8 vf[4][2];
#pragma unroll
    for (int t = 0; t < 4; t++)
#pragma unroll
      for (int ks = 0; ks < 2; ks++) {
        const unsigned short* base = Vl + (t * 16 + lr) * 64;
        short4v lo = *(const short4v*)(base + ((ks * 32 + g * 4) ^ sw));
        short4v hi = *(const short4v*)(base + ((ks * 32 + 16 + g * 4) ^ sw));
        short8 v;
        v[0] = lo[0]; v[1] = lo[1]; v[2] = lo[2]; v[3] = lo[3];
        v[4] = hi[0]; v[5] = hi[1]; v[6] = hi[2]; v[7] = hi[3];
        vf[t][ks] = v;
      }

#pragma unroll
    for (int qt = 0; qt < 2; qt++) {
      f32x4 va[4];
#pragma unroll
      for (int st = 0; st < 4; st++) va[st] = sc[qt][st] * c2 + mbv[st];
      f32x4 vm = vmax4(vmax4(va[0], va[1]), vmax4(va[2], va[3]));
      float mx = fmaxf(fmaxf(vm[0], vm[1]), fmaxf(vm[2], vm[3]));
      mx = fmaxf(mx, __shfl_xor(mx, 16));
      mx = fmaxf(mx, __shfl_xor(mx, 32));
      if (__any(mx > mrun[qt] + 12.0f)) {
        float mnew = fmaxf(mrun[qt], mx);
        float scl = exp2f(mrun[qt] - mnew);
        mrun[qt] = mnew;
        lrun[qt] *= scl;
#pragma unroll
        for (int t = 0; t < 4; t++) o[qt][t] *= scl;
      }
      f32x4 pv[4];
#pragma unroll
      for (int st = 0; st < 4; st++) {
        f32x4 x = va[st] - mrun[qt];
#pragma unroll
        for (int e = 0; e < 4; e++) pv[st][e] = exp2f(x[e]);
      }
      f32x4 s4 = (pv[0] + pv[1]) + (pv[2] + pv[3]);
      float ps = (s4[0] + s4[1]) + (s4[2] + s4[3]);
      ps += __shfl_xor(ps, 16);
      ps += __shfl_xor(ps, 32);
      lrun[qt] += ps;
      union { short8 s8; unsigned u[4]; } pk0, pk1;
      pk0.u[0] = pk2bf(pv[0][0], pv[0][1]); pk0.u[1] = pk2bf(pv[0][2], pv[0][3]);
      pk0.u[2] = pk2bf(pv[1][0], pv[1][1]); pk0.u[3] = pk2bf(pv[1][2], pv[1][3]);
      pk1.u[0] = pk2bf(pv[2][0], pv[2][1]); pk1.u[1] = pk2bf(pv[2][2], pv[2][3]);
      pk1.u[2] = pk2bf(pv[3][0], pv[3][1]); pk1.u[3] = pk2bf(pv[3][2], pv[3][3]);
#pragma unroll
      for (int t = 0; t < 4; t++) {
        o[qt][t] = __builtin_amdgcn_mfma_f32_16x16x32_bf16(vf[t][0], pk0.s8, o[qt][t], 0, 0, 0);
        o[qt][t] = __builtin_amdgcn_mfma_f32_16x16x32_bf16(vf[t][1], pk1.s8, o[qt][t], 0, 0, 0);
      }
    }
    __syncthreads();
  }

#pragma unroll
  for (int qt = 0; qt < 2; qt++) {
    float inv = lrun[qt] > 0.f ? 1.f / lrun[qt] : 0.f;
    size_t row = (size_t)b_ * 2048 + qbase + qt * 16 + lr;
#pragma unroll
    for (int t = 0; t < 4; t++) {
      short4v pkv;
#pragma unroll
      for (int i = 0; i < 4; i++) pkv[i] = (short)f2bf(o[qt][t][i] * inv);
      *(short4v*)(AO + row * 1024 + h * 64 + t * 16 + g * 4) = pkv;
    }
  }
}

// ---------------- launch ----------------
extern "C" void kernel_launch(void* const* d_in, const int* in_sizes, int n_in,
                              void* d_out, int out_size, void* d_ws, size_t ws_size,
                              hipStream_t stream) {
  const float* q_x = (const float*)d_in[0];
  const float* k_x = (const float*)d_in[1];
  const float* v_x = (const float*)d_in[2];
  const float* energy = (const float*)d_in[3];
  const float* Wq = (const float*)d_in[4];
  const float* bq = (const float*)d_in[5];
  const float* Wk = (const float*)d_in[6];
  const float* bk = (const float*)d_in[7];
  const float* Wv = (const float*)d_in[8];
  const float* bv = (const float*)d_in[9];
  const float* Wo = (const float*)d_in[10];
  const float* bo = (const float*)d_in[11];

  char* w = (char*)d_ws;
  auto take = [&](size_t bytes) {
    char* p = w;
    w += (bytes + 255) & ~(size_t)255;
    return p;
  };
  const size_t XB = (size_t)8192 * 1024 * 2;
  unsigned short* Xq = (unsigned short*)take(XB);
  unsigned short* Xk = (unsigned short*)take(XB);
  unsigned short* Xv = (unsigned short*)take(XB);
  unsigned short* Wtq = (unsigned short*)take((size_t)1024 * 1024 * 2);
  unsigned short* Wtk = (unsigned short*)take((size_t)1024 * 1024 * 2);
  unsigned short* Wtv = (unsigned short*)take((size_t)1024 * 1024 * 2);
  unsigned short* Wto = (unsigned short*)take((size_t)1024 * 1024 * 2);
  float* mb = (float*)take((size_t)4 * 2048 * 4);
  unsigned short* Qh = (unsigned short*)take(XB);
  unsigned short* Kh = (unsigned short*)take(XB);
  unsigned short* Vt = (unsigned short*)take(XB);
  unsigned short* AO = (unsigned short*)take(XB);

  const int NX = 8192 * 1024;
  conv_bf16_kernel<<<NX / 1024, 256, 0, stream>>>(q_x, Xq, NX);
  conv_bf16_kernel<<<NX / 1024, 256, 0, stream>>>(k_x, Xk, NX);
  conv_bf16_kernel<<<NX / 1024, 256, 0, stream>>>(v_x, Xv, NX);
  wtrans_kernel<<<dim3(32, 32), dim3(32, 8), 0, stream>>>(Wq, Wtq);
  wtrans_kernel<<<dim3(32, 32), dim3(32, 8), 0, stream>>>(Wk, Wtk);
  wtrans_kernel<<<dim3(32, 32), dim3(32, 8), 0, stream>>>(Wv, Wtv);
  wtrans_kernel<<<dim3(32, 32), dim3(32, 8), 0, stream>>>(Wo, Wto);
  mask_kernel<<<32, 256, 0, stream>>>(energy, mb, 8192);

  gemm128_kernel<0><<<dim3(64, 8), 256, 0, stream>>>(Xq, Wtq, bq, (void*)Qh);
  gemm128_kernel<0><<<dim3(64, 8), 256, 0, stream>>>(Xk, Wtk, bk, (void*)Kh);
  gemm128_kernel<1><<<dim3(64, 8), 256, 0, stream>>>(Xv, Wtv, bv, (void*)Vt);
  attn_kernel<<<dim3(16, 64), 256, 0, stream>>>(Qh, Kh, Vt, mb, AO);
  gemm128_kernel<2><<<dim3(64, 8), 256, 0, stream>>>(AO, Wto, bo, d_out);
}